// Round 13
// baseline (58.688 us; speedup 1.0000x reference)
//
#include <hip/hip_runtime.h>
#include <math.h>

#define QN 900
#define TN 100
#define CN 91
#define PN 1024
#define HWD 128
#define BS 2

#define AS1 __attribute__((address_space(1)))
#define AS3 __attribute__((address_space(3)))

__device__ __forceinline__ float sigmoidf_(float x) {
    return 1.0f / (1.0f + __expf(-x));
}
__device__ __forceinline__ float softplusf_(float x) {
    return fmaxf(x, 0.0f) + __logf(1.0f + __expf(-fabsf(x)));
}
__device__ __forceinline__ unsigned bfhi(float f) {   // RNE bf16 in HIGH 16 bits
    unsigned u = __float_as_uint(f);
    return (u + 0x7FFFu + ((u >> 16) & 1u)) & 0xFFFF0000u;
}

// ---------------------------------------------------------------------------
// Prep: 200 blocks: tm bit-pack + popcount sums (nearest sampling).
// ---------------------------------------------------------------------------
__global__ __launch_bounds__(256) void prep_kernel(
    const float2* __restrict__ coords, const int* __restrict__ tmasks,
    unsigned* __restrict__ tmw, float* __restrict__ tmsum)
{
    __shared__ int cnt[4];
    const int bx = blockIdx.x;
    const int tid = threadIdx.x;
    const int wv = tid >> 6, lane = tid & 63;
    const int b = bx / TN, t = bx % TN;
    const int* m = tmasks + (size_t)(b * TN + t) * (HWD * HWD);
    int addr[4]; unsigned vld[4];
#pragma unroll
    for (int c = 0; c < 4; ++c) {
        float2 cd = coords[b * PN + c * 256 + tid];
        int xi = (int)rintf(cd.x * (float)HWD - 0.5f);
        int yi = (int)rintf(cd.y * (float)HWD - 0.5f);
        vld[c] = (xi >= 0) & (xi < HWD) & (yi >= 0) & (yi < HWD);
        addr[c] = min(max(yi, 0), HWD - 1) * HWD + min(max(xi, 0), HWD - 1);
    }
    int rv[4];
#pragma unroll
    for (int c = 0; c < 4; ++c) rv[c] = m[addr[c]];
    int mycnt = 0;
#pragma unroll
    for (int c = 0; c < 4; ++c) {
        unsigned long long bal = __ballot(vld[c] && (rv[c] != 0));
        if (lane == 0) {
            tmw[(size_t)(b * TN + t) * 32 + c * 8 + wv * 2 + 0] = (unsigned)(bal & 0xFFFFFFFFull);
            tmw[(size_t)(b * TN + t) * 32 + c * 8 + wv * 2 + 1] = (unsigned)(bal >> 32);
            mycnt += __popcll(bal);
        }
    }
    if (lane == 0) cnt[wv] = mycnt;
    __syncthreads();
    if (tid == 0)
        tmsum[b * TN + t] = (float)((cnt[0] + cnt[1]) + (cnt[2] + cnt[3]));
}

// ---------------------------------------------------------------------------
// Main: one block (256 thr) per (b,q). Scattered bilinear taps fetched via
// global_load_lds (size=4, per-lane global addr) -> taps LDS: in-flight data
// lives in the DMA queue, NOT VGPRs -> no spill pressure, full MLP. Single
// vmcnt(0) drain, conflict-free ds_read readback, then r11's packed bit-GEMM
// + fused epilogue.
// ---------------------------------------------------------------------------
__global__ __launch_bounds__(256, 4) void main_kernel(
    const float* __restrict__ logits, const float4* __restrict__ pboxes,
    const int* __restrict__ labels, const float4* __restrict__ tboxes,
    const float* __restrict__ pmasks, const float2* __restrict__ coords,
    const unsigned* __restrict__ tmw, const float* __restrict__ tmsum_,
    float* __restrict__ out, float* __restrict__ blockmax,
    int* __restrict__ badflag)
{
    __shared__ __align__(16) float taps[16][256];   // 16 KB: (c*4+tap) x thread
    __shared__ unsigned pl[PN];                     // 4 KB packed (bf16 pm|sg)
    __shared__ float part[8][32][9];                // 9.2 KB stride-9
    __shared__ float sred[8];
    __shared__ float mred[256];
    __shared__ int sbad;

    const int bq = blockIdx.x;
    const int b = bq / QN, q = bq - b * QN;
    const int tid = threadIdx.x;
    const int wv = tid >> 6, lane = tid & 63;
    const int pc = tid >> 5, ts = tid & 31;
    const float* mask = pmasks + (size_t)bq * (HWD * HWD);

    if (tid == 0) sbad = 0;

    // ---- compute addresses and fire 16 scattered DMA gathers ----
    float wxa[4], wya[4];
    unsigned fl[4];
#pragma unroll
    for (int c = 0; c < 4; ++c) {
        float2 cd = coords[b * PN + c * 256 + tid];
        float x = cd.x * (float)HWD - 0.5f;
        float y = cd.y * (float)HWD - 0.5f;
        float fx = floorf(x), fy = floorf(y);
        int x0 = (int)fx, y0 = (int)fy;
        int x1 = x0 + 1, y1 = y0 + 1;
        wxa[c] = x - fx; wya[c] = y - fy;
        int xc0 = min(max(x0, 0), HWD - 1), xc1 = min(max(x1, 0), HWD - 1);
        int yc0 = min(max(y0, 0), HWD - 1), yc1 = min(max(y1, 0), HWD - 1);
        fl[c] = (unsigned)((x0 >= 0) & (x0 < HWD))
              | ((unsigned)((x1 >= 0) & (x1 < HWD)) << 1)
              | ((unsigned)((y0 >= 0) & (y0 < HWD)) << 2)
              | ((unsigned)((y1 >= 0) & (y1 < HWD)) << 3);
        const int a00 = yc0 * HWD + xc0, a01 = yc0 * HWD + xc1;
        const int a10 = yc1 * HWD + xc0, a11 = yc1 * HWD + xc1;
        __builtin_amdgcn_global_load_lds((AS1 const void*)(mask + a00),
                                         (AS3 void*)&taps[c * 4 + 0][wv * 64], 4, 0, 0);
        __builtin_amdgcn_global_load_lds((AS1 const void*)(mask + a01),
                                         (AS3 void*)&taps[c * 4 + 1][wv * 64], 4, 0, 0);
        __builtin_amdgcn_global_load_lds((AS1 const void*)(mask + a10),
                                         (AS3 void*)&taps[c * 4 + 2][wv * 64], 4, 0, 0);
        __builtin_amdgcn_global_load_lds((AS1 const void*)(mask + a11),
                                         (AS3 void*)&taps[c * 4 + 3][wv * 64], 4, 0, 0);
    }

    // ---- under the DMA shadow: tmw words + epilogue scalars (to regs) ----
    const unsigned* rowb = tmw + (size_t)b * TN * 32;
    unsigned w0[4], w1[4], w2[4], w3[4];
#pragma unroll
    for (int g = 0; g < 4; ++g) {
        w0[g] = rowb[(ts +  0) * 32 + pc * 4 + g];
        w1[g] = rowb[(ts + 32) * 32 + pc * 4 + g];
        w2[g] = rowb[(ts + 64) * 32 + pc * 4 + g];
        w3[g] = (ts + 96 < TN) ? rowb[(ts + 96) * 32 + pc * 4 + g] : 0u;
    }
    float lg = 0.f, tsum = 0.f;
    float4 tb = make_float4(0, 0, 0, 0), pb = make_float4(0, 0, 0, 0);
    if (tid < TN) {
        int lab = labels[b * TN + tid];
        lg = logits[(size_t)(b * QN + q) * CN + lab];
        tsum = tmsum_[b * TN + tid];
        tb = tboxes[b * TN + tid];
        pb = pboxes[b * QN + q];
    }

    // ---- drain DMAs; each wave reads back only its own lanes' taps ----
    asm volatile("s_waitcnt vmcnt(0)" ::: "memory");

    float lsp = 0.f, lsm = 0.f;
#pragma unroll
    for (int c = 0; c < 4; ++c) {
        float v00 = taps[c * 4 + 0][tid];
        float v01 = taps[c * 4 + 1][tid];
        float v10 = taps[c * 4 + 2][tid];
        float v11 = taps[c * 4 + 3][tid];
        v00 = (fl[c] & 1u) && (fl[c] & 4u) ? v00 : 0.f;
        v01 = (fl[c] & 2u) && (fl[c] & 4u) ? v01 : 0.f;
        v10 = (fl[c] & 1u) && (fl[c] & 8u) ? v10 : 0.f;
        v11 = (fl[c] & 2u) && (fl[c] & 8u) ? v11 : 0.f;
        float wx = wxa[c], wy = wya[c];
        float pm = (v00 * (1.f - wx) + v01 * wx) * (1.f - wy) +
                   (v10 * (1.f - wx) + v11 * wx) * wy;
        float sg = sigmoidf_(pm);
        lsp += softplusf_(pm);
        lsm += sg;
        pl[c * 256 + tid] = bfhi(pm) | (bfhi(sg) >> 16);
    }
    for (int off = 32; off > 0; off >>= 1) {
        lsp += __shfl_down(lsp, off);
        lsm += __shfl_down(lsm, off);
    }
    if (lane == 0) { sred[wv * 2 + 0] = lsp; sred[wv * 2 + 1] = lsm; }
    __syncthreads();
    float s_sp = (sred[0] + sred[2]) + (sred[4] + sred[6]);
    float s_sm = (sred[1] + sred[3]) + (sred[5] + sred[7]);

    // ---- bit-masked dual GEMM, 2-deep prefetched uint4 stream ----
    float a0 = 0, a1 = 0, a2 = 0, a3 = 0, a4 = 0, a5 = 0, a6 = 0, a7 = 0;
    {
        const uint4* plv = (const uint4*)&pl[pc * 128];
        uint4 ua = plv[0];
        uint4 ub = plv[1];
#pragma unroll
        for (int it = 0; it < 32; ++it) {
            const int g = it >> 3, sh = (it & 7) * 4;
            uint4 ucur = ua;
            ua = ub;
            if (it < 30) ub = plv[it + 2];
            unsigned q0 = w0[g] >> sh;
            unsigned q1 = w1[g] >> sh;
            unsigned q2 = w2[g] >> sh;
            unsigned q3 = w3[g] >> sh;
#pragma unroll
            for (int k = 0; k < 4; ++k) {
                unsigned uv = (k == 0) ? ucur.x : (k == 1) ? ucur.y : (k == 2) ? ucur.z : ucur.w;
                float pmv = __uint_as_float(uv & 0xFFFF0000u);
                float sgv = __uint_as_float(uv << 16);
                float f0 = (float)((q0 >> k) & 1u);
                float f1 = (float)((q1 >> k) & 1u);
                float f2 = (float)((q2 >> k) & 1u);
                float f3 = (float)((q3 >> k) & 1u);
                a0 = fmaf(pmv, f0, a0); a1 = fmaf(sgv, f0, a1);
                a2 = fmaf(pmv, f1, a2); a3 = fmaf(sgv, f1, a3);
                a4 = fmaf(pmv, f2, a4); a5 = fmaf(sgv, f2, a5);
                a6 = fmaf(pmv, f3, a6); a7 = fmaf(sgv, f3, a7);
            }
        }
    }
    part[pc][ts][0] = a0; part[pc][ts][1] = a1;
    part[pc][ts][2] = a2; part[pc][ts][3] = a3;
    part[pc][ts][4] = a4; part[pc][ts][5] = a5;
    part[pc][ts][6] = a6; part[pc][ts][7] = a7;
    __syncthreads();

    // ---- epilogue ----
    float val = -INFINITY;
    if (tid < TN) {
        int t = tid, tss = t & 31, kk = t >> 5;
        float apm = 0.f, asg = 0.f;
#pragma unroll
        for (int pp = 0; pp < 8; ++pp) {
            apm += part[pp][tss][kk * 2 + 0];
            asg += part[pp][tss][kk * 2 + 1];
        }
        float ce = (s_sp - apm) * (1.0f / (float)PN);
        float dice = 1.0f - (2.0f * asg + 1.0f) / (s_sm + tsum + 1.0f);

        float pr = sigmoidf_(lg);
        float cls = 0.25f * (1.f - pr) * (1.f - pr) * softplusf_(-lg)
                  - 0.75f * pr * pr * softplusf_(lg);

        float l1 = fabsf(pb.x - tb.x) + fabsf(pb.y - tb.y) +
                   fabsf(pb.z - tb.z) + fabsf(pb.w - tb.w);

        float px1 = pb.x - 0.5f * pb.z, py1 = pb.y - 0.5f * pb.w;
        float px2 = pb.x + 0.5f * pb.z, py2 = pb.y + 0.5f * pb.w;
        float tx1 = tb.x - 0.5f * tb.z, ty1 = tb.y - 0.5f * tb.w;
        float tx2 = tb.x + 0.5f * tb.z, ty2 = tb.y + 0.5f * tb.w;
        float A1 = (px2 - px1) * (py2 - py1);
        float A2 = (tx2 - tx1) * (ty2 - ty1);
        float iw = fmaxf(fminf(px2, tx2) - fmaxf(px1, tx1), 0.f);
        float ih = fmaxf(fminf(py2, ty2) - fmaxf(py1, ty1), 0.f);
        float inter = iw * ih;
        float uni = A1 + A2 - inter;
        float iou = inter / uni;
        float cw = fmaxf(fmaxf(px2, tx2) - fminf(px1, tx1), 0.f);
        float chh = fmaxf(fmaxf(py2, ty2) - fminf(py1, ty1), 0.f);
        float area = cw * chh;
        float giou = iou - (area - uni) / area;

        float Cv = l1 + cls - giou + ce + dice;
        out[(size_t)(b * QN + q) * TN + t] = Cv;
        if (isfinite(Cv)) val = Cv;
        else sbad = 1;             // benign same-value race
    }
    mred[tid] = val;
    __syncthreads();
    if (tid < 64) {
        float m = fmaxf(fmaxf(mred[tid], mred[tid + 64]),
                        fmaxf(mred[tid + 128], mred[tid + 192]));
        for (int off = 32; off > 0; off >>= 1)
            m = fmaxf(m, __shfl_down(m, off));
        if (tid == 0) { blockmax[bq] = m; badflag[bq] = sbad; }
    }
}

// ---------------------------------------------------------------------------
// Fixup: C = where(finite, C, 2*max_finite) per batch. Gated by per-row flag.
// ---------------------------------------------------------------------------
__global__ __launch_bounds__(128) void fix_kernel(float* __restrict__ out,
                                                  const float* __restrict__ blockmax,
                                                  const int* __restrict__ badflag)
{
    const int bq = blockIdx.x;
    if (badflag[bq] == 0) return;       // uniform early exit
    const int tid = threadIdx.x;
    if (tid >= TN) return;
    const int b = bq / QN;
    float v = out[(size_t)bq * TN + tid];
    if (!isfinite(v)) {
        float m = -INFINITY;
        for (int k = 0; k < QN; ++k) m = fmaxf(m, blockmax[b * QN + k]);
        out[(size_t)bq * TN + tid] = 2.0f * m;
    }
}

extern "C" void kernel_launch(void* const* d_in, const int* in_sizes, int n_in,
                              void* d_out, int out_size, void* d_ws, size_t ws_size,
                              hipStream_t stream) {
    const float* logits  = (const float*)d_in[0];
    const float4* pboxes = (const float4*)d_in[1];
    const int* labels    = (const int*)d_in[2];
    const float4* tboxes = (const float4*)d_in[3];
    const float* pmasks  = (const float*)d_in[4];
    const int* tmasks    = (const int*)d_in[5];
    const float* coords  = (const float*)d_in[6];
    float* out = (float*)d_out;

    char* ws = (char*)d_ws;
    unsigned* tmw   = (unsigned*)(ws);            // 25600 B
    float* tmsum    = (float*)(ws + 25600);       // 800 B
    float* blockmax = (float*)(ws + 26400);       // 7200 B
    int* badflag    = (int*)(ws + 33600);         // 7200 B

    hipLaunchKernelGGL(prep_kernel, dim3(BS * TN), dim3(256), 0, stream,
                       (const float2*)coords, tmasks, tmw, tmsum);
    hipLaunchKernelGGL(main_kernel, dim3(BS * QN), dim3(256), 0, stream,
                       logits, pboxes, labels, tboxes, pmasks, (const float2*)coords,
                       tmw, tmsum, out, blockmax, badflag);
    hipLaunchKernelGGL(fix_kernel, dim3(BS * QN), dim3(128), 0, stream,
                       out, blockmax, badflag);
}

// Round 14
// 53.238 us; speedup vs baseline: 1.1024x; 1.1024x over previous
//
#include <hip/hip_runtime.h>
#include <math.h>

#define QN 900
#define TN 100
#define CN 91
#define PN 1024
#define HWD 128
#define BS 2

typedef float f32x2 __attribute__((ext_vector_type(2)));

__device__ __forceinline__ float sigmoidf_(float x) {
    return 1.0f / (1.0f + __expf(-x));
}
__device__ __forceinline__ float softplusf_(float x) {
    return fmaxf(x, 0.0f) + __logf(1.0f + __expf(-fabsf(x)));
}
__device__ __forceinline__ unsigned bfhi(float f) {   // RNE bf16 in HIGH 16 bits
    unsigned u = __float_as_uint(f);
    return (u + 0x7FFFu + ((u >> 16) & 1u)) & 0xFFFF0000u;
}

// ---------------------------------------------------------------------------
// Prep: 200 blocks: tm bit-pack + popcount sums (nearest sampling).
// ---------------------------------------------------------------------------
__global__ __launch_bounds__(256) void prep_kernel(
    const float2* __restrict__ coords, const int* __restrict__ tmasks,
    unsigned* __restrict__ tmw, float* __restrict__ tmsum)
{
    __shared__ int cnt[4];
    const int bx = blockIdx.x;
    const int tid = threadIdx.x;
    const int wv = tid >> 6, lane = tid & 63;
    const int b = bx / TN, t = bx % TN;
    const int* m = tmasks + (size_t)(b * TN + t) * (HWD * HWD);
    int addr[4]; unsigned vld[4];
#pragma unroll
    for (int c = 0; c < 4; ++c) {
        float2 cd = coords[b * PN + c * 256 + tid];
        int xi = (int)rintf(cd.x * (float)HWD - 0.5f);
        int yi = (int)rintf(cd.y * (float)HWD - 0.5f);
        vld[c] = (xi >= 0) & (xi < HWD) & (yi >= 0) & (yi < HWD);
        addr[c] = min(max(yi, 0), HWD - 1) * HWD + min(max(xi, 0), HWD - 1);
    }
    int rv[4];
#pragma unroll
    for (int c = 0; c < 4; ++c) rv[c] = m[addr[c]];
    int mycnt = 0;
#pragma unroll
    for (int c = 0; c < 4; ++c) {
        unsigned long long bal = __ballot(vld[c] && (rv[c] != 0));
        if (lane == 0) {
            tmw[(size_t)(b * TN + t) * 32 + c * 8 + wv * 2 + 0] = (unsigned)(bal & 0xFFFFFFFFull);
            tmw[(size_t)(b * TN + t) * 32 + c * 8 + wv * 2 + 1] = (unsigned)(bal >> 32);
            mycnt += __popcll(bal);
        }
    }
    if (lane == 0) cnt[wv] = mycnt;
    __syncthreads();
    if (tid == 0)
        tmsum[b * TN + t] = (float)((cnt[0] + cnt[1]) + (cnt[2] + cnt[3]));
}

// ---------------------------------------------------------------------------
// Main: one block (256 thr) per (b,q). Round-7 structure (stable VGPR-48;
// launch_bounds MUST stay (256,4)). Change: the two x-taps per bilinear row
// are loaded as ONE float2 (adjacent floats) -> 8 scattered requests/thread
// instead of 16. Edge cases handled by loading at xl=clamp(x0,0,126) and
// selecting lanes; validity still via flag bits.
// ---------------------------------------------------------------------------
__global__ __launch_bounds__(256, 4) void main_kernel(
    const float* __restrict__ logits, const float4* __restrict__ pboxes,
    const int* __restrict__ labels, const float4* __restrict__ tboxes,
    const float* __restrict__ pmasks, const float2* __restrict__ coords,
    const unsigned* __restrict__ tmw, const float* __restrict__ tmsum_,
    float* __restrict__ out, float* __restrict__ blockmax,
    int* __restrict__ badflag)
{
    __shared__ unsigned pl[PN];            // 4 KB packed (bf16 pm | bf16 sg)
    __shared__ float part[8][32][9];       // 9.2 KB (stride-9: conflict-free)
    __shared__ float sred[8];
    __shared__ float mred[256];
    __shared__ int sbad;

    const int bq = blockIdx.x;
    const int b = bq / QN, q = bq - b * QN;
    const int tid = threadIdx.x;
    const int wv = tid >> 6, lane = tid & 63;
    const int pc = tid >> 5, ts = tid & 31;
    const float* mask = pmasks + (size_t)bq * (HWD * HWD);

    if (tid == 0) sbad = 0;

    // ---- addresses for 4 points/thread (row-pair form) ----
    int ar0[4], ar1[4];        // float2 element offsets for rows y0, y1
    int x0a[4];
    float wxa[4], wya[4];
    unsigned fl[4];
#pragma unroll
    for (int c = 0; c < 4; ++c) {
        float2 cd = coords[b * PN + c * 256 + tid];
        float x = cd.x * (float)HWD - 0.5f;
        float y = cd.y * (float)HWD - 0.5f;
        float fx = floorf(x), fy = floorf(y);
        int x0 = (int)fx, y0 = (int)fy;
        int x1 = x0 + 1, y1 = y0 + 1;
        wxa[c] = x - fx; wya[c] = y - fy;
        x0a[c] = x0;
        int xl = min(max(x0, 0), HWD - 2);             // pair base: [xl, xl+1]
        int yc0 = min(max(y0, 0), HWD - 1), yc1 = min(max(y1, 0), HWD - 1);
        ar0[c] = yc0 * HWD + xl;
        ar1[c] = yc1 * HWD + xl;
        fl[c] = (unsigned)((x0 >= 0) & (x0 < HWD))
              | ((unsigned)((x1 >= 0) & (x1 < HWD)) << 1)
              | ((unsigned)((y0 >= 0) & (y0 < HWD)) << 2)
              | ((unsigned)((y1 >= 0) & (y1 < HWD)) << 3);
    }

    // ---- issue ALL 8 paired scattered loads up front ----
    f32x2 p0[4], p1[4];
#pragma unroll
    for (int c = 0; c < 4; ++c) {
        p0[c] = *(const f32x2*)(mask + ar0[c]);
        p1[c] = *(const f32x2*)(mask + ar1[c]);
    }

    // ---- under the shadow: tmw words + epilogue scalars ----
    const unsigned* rowb = tmw + (size_t)b * TN * 32;
    unsigned w0[4], w1[4], w2[4], w3[4];
#pragma unroll
    for (int g = 0; g < 4; ++g) {
        w0[g] = rowb[(ts +  0) * 32 + pc * 4 + g];
        w1[g] = rowb[(ts + 32) * 32 + pc * 4 + g];
        w2[g] = rowb[(ts + 64) * 32 + pc * 4 + g];
        w3[g] = (ts + 96 < TN) ? rowb[(ts + 96) * 32 + pc * 4 + g] : 0u;
    }
    float lg = 0.f, tsum = 0.f;
    float4 tb = make_float4(0, 0, 0, 0), pb = make_float4(0, 0, 0, 0);
    if (tid < TN) {
        int lab = labels[b * TN + tid];
        lg = logits[(size_t)(b * QN + q) * CN + lab];
        tsum = tmsum_[b * TN + tid];
        tb = tboxes[b * TN + tid];
        pb = pboxes[b * QN + q];
    }

    // ---- bilinear combine + pointwise transcendental -> packed LDS ----
    float lsp = 0.f, lsm = 0.f;
#pragma unroll
    for (int c = 0; c < 4; ++c) {
        // x0 maps to pair.x unless x0 was clamped down (x0==127 -> pair.y);
        // x1 maps to pair.y unless x0==-1 (then x1==xl -> pair.x).
        const bool x0hi = (x0a[c] >= HWD - 1);   // x0==127 (x1 invalid then)
        const bool x1lo = (x0a[c] < 0);          // x0==-1  (x0 invalid then)
        float v00 = x0hi ? p0[c].y : p0[c].x;
        float v01 = x1lo ? p0[c].x : p0[c].y;
        float v10 = x0hi ? p1[c].y : p1[c].x;
        float v11 = x1lo ? p1[c].x : p1[c].y;
        const bool bx0 = fl[c] & 1u, bx1 = fl[c] & 2u, by0 = fl[c] & 4u, by1 = fl[c] & 8u;
        v00 = (by0 && bx0) ? v00 : 0.f;
        v01 = (by0 && bx1) ? v01 : 0.f;
        v10 = (by1 && bx0) ? v10 : 0.f;
        v11 = (by1 && bx1) ? v11 : 0.f;
        float wx = wxa[c], wy = wya[c];
        float pm = (v00 * (1.f - wx) + v01 * wx) * (1.f - wy) +
                   (v10 * (1.f - wx) + v11 * wx) * wy;
        float sg = sigmoidf_(pm);
        lsp += softplusf_(pm);
        lsm += sg;
        pl[c * 256 + tid] = bfhi(pm) | (bfhi(sg) >> 16);
    }
    for (int off = 32; off > 0; off >>= 1) {
        lsp += __shfl_down(lsp, off);
        lsm += __shfl_down(lsm, off);
    }
    if (lane == 0) { sred[wv * 2 + 0] = lsp; sred[wv * 2 + 1] = lsm; }
    __syncthreads();
    float s_sp = (sred[0] + sred[2]) + (sred[4] + sred[6]);
    float s_sm = (sred[1] + sred[3]) + (sred[5] + sred[7]);

    // ---- bit-masked dual GEMM: chunk pc (128 points) x 4 targets ----
    float a0 = 0, a1 = 0, a2 = 0, a3 = 0, a4 = 0, a5 = 0, a6 = 0, a7 = 0;
#pragma unroll
    for (int g = 0; g < 4; ++g) {
        unsigned u0 = w0[g], u1 = w1[g], u2 = w2[g], u3 = w3[g];
        int p0i = pc * 128 + g * 32;
#pragma unroll
        for (int jj = 0; jj < 8; ++jj) {
            uint4 u = *(const uint4*)&pl[p0i + jj * 4];   // broadcast within half-wave
#pragma unroll
            for (int k = 0; k < 4; ++k) {
                unsigned uv = (k == 0) ? u.x : (k == 1) ? u.y : (k == 2) ? u.z : u.w;
                float pmv = __uint_as_float(uv & 0xFFFF0000u);
                float sgv = __uint_as_float(uv << 16);
                float f0 = (float)((u0 >> k) & 1u);
                float f1 = (float)((u1 >> k) & 1u);
                float f2 = (float)((u2 >> k) & 1u);
                float f3 = (float)((u3 >> k) & 1u);
                a0 = fmaf(pmv, f0, a0); a1 = fmaf(sgv, f0, a1);
                a2 = fmaf(pmv, f1, a2); a3 = fmaf(sgv, f1, a3);
                a4 = fmaf(pmv, f2, a4); a5 = fmaf(sgv, f2, a5);
                a6 = fmaf(pmv, f3, a6); a7 = fmaf(sgv, f3, a7);
            }
            u0 >>= 4; u1 >>= 4; u2 >>= 4; u3 >>= 4;
        }
    }
    part[pc][ts][0] = a0; part[pc][ts][1] = a1;
    part[pc][ts][2] = a2; part[pc][ts][3] = a3;
    part[pc][ts][4] = a4; part[pc][ts][5] = a5;
    part[pc][ts][6] = a6; part[pc][ts][7] = a7;
    __syncthreads();

    // ---- epilogue ----
    float val = -INFINITY;
    if (tid < TN) {
        int t = tid, tss = t & 31, kk = t >> 5;
        float apm = 0.f, asg = 0.f;
#pragma unroll
        for (int pp = 0; pp < 8; ++pp) {
            apm += part[pp][tss][kk * 2 + 0];
            asg += part[pp][tss][kk * 2 + 1];
        }
        float ce = (s_sp - apm) * (1.0f / (float)PN);
        float dice = 1.0f - (2.0f * asg + 1.0f) / (s_sm + tsum + 1.0f);

        float pr = sigmoidf_(lg);
        float cls = 0.25f * (1.f - pr) * (1.f - pr) * softplusf_(-lg)
                  - 0.75f * pr * pr * softplusf_(lg);

        float l1 = fabsf(pb.x - tb.x) + fabsf(pb.y - tb.y) +
                   fabsf(pb.z - tb.z) + fabsf(pb.w - tb.w);

        float px1 = pb.x - 0.5f * pb.z, py1 = pb.y - 0.5f * pb.w;
        float px2 = pb.x + 0.5f * pb.z, py2 = pb.y + 0.5f * pb.w;
        float tx1 = tb.x - 0.5f * tb.z, ty1 = tb.y - 0.5f * tb.w;
        float tx2 = tb.x + 0.5f * tb.z, ty2 = tb.y + 0.5f * tb.w;
        float A1 = (px2 - px1) * (py2 - py1);
        float A2 = (tx2 - tx1) * (ty2 - ty1);
        float iw = fmaxf(fminf(px2, tx2) - fmaxf(px1, tx1), 0.f);
        float ih = fmaxf(fminf(py2, ty2) - fmaxf(py1, ty1), 0.f);
        float inter = iw * ih;
        float uni = A1 + A2 - inter;
        float iou = inter / uni;
        float cw = fmaxf(fmaxf(px2, tx2) - fminf(px1, tx1), 0.f);
        float chh = fmaxf(fmaxf(py2, ty2) - fminf(py1, ty1), 0.f);
        float area = cw * chh;
        float giou = iou - (area - uni) / area;

        float Cv = l1 + cls - giou + ce + dice;
        out[(size_t)(b * QN + q) * TN + t] = Cv;
        if (isfinite(Cv)) val = Cv;
        else sbad = 1;             // benign same-value race
    }
    mred[tid] = val;
    __syncthreads();
    if (tid < 64) {
        float m = fmaxf(fmaxf(mred[tid], mred[tid + 64]),
                        fmaxf(mred[tid + 128], mred[tid + 192]));
        for (int off = 32; off > 0; off >>= 1)
            m = fmaxf(m, __shfl_down(m, off));
        if (tid == 0) { blockmax[bq] = m; badflag[bq] = sbad; }
    }
}

// ---------------------------------------------------------------------------
// Fixup: C = where(finite, C, 2*max_finite) per batch. Gated by per-row flag.
// ---------------------------------------------------------------------------
__global__ __launch_bounds__(128) void fix_kernel(float* __restrict__ out,
                                                  const float* __restrict__ blockmax,
                                                  const int* __restrict__ badflag)
{
    const int bq = blockIdx.x;
    if (badflag[bq] == 0) return;       // uniform early exit
    const int tid = threadIdx.x;
    if (tid >= TN) return;
    const int b = bq / QN;
    float v = out[(size_t)bq * TN + tid];
    if (!isfinite(v)) {
        float m = -INFINITY;
        for (int k = 0; k < QN; ++k) m = fmaxf(m, blockmax[b * QN + k]);
        out[(size_t)bq * TN + tid] = 2.0f * m;
    }
}

extern "C" void kernel_launch(void* const* d_in, const int* in_sizes, int n_in,
                              void* d_out, int out_size, void* d_ws, size_t ws_size,
                              hipStream_t stream) {
    const float* logits  = (const float*)d_in[0];
    const float4* pboxes = (const float4*)d_in[1];
    const int* labels    = (const int*)d_in[2];
    const float4* tboxes = (const float4*)d_in[3];
    const float* pmasks  = (const float*)d_in[4];
    const int* tmasks    = (const int*)d_in[5];
    const float* coords  = (const float*)d_in[6];
    float* out = (float*)d_out;

    char* ws = (char*)d_ws;
    unsigned* tmw   = (unsigned*)(ws);            // 25600 B
    float* tmsum    = (float*)(ws + 25600);       // 800 B
    float* blockmax = (float*)(ws + 26400);       // 7200 B
    int* badflag    = (int*)(ws + 33600);         // 7200 B

    hipLaunchKernelGGL(prep_kernel, dim3(BS * TN), dim3(256), 0, stream,
                       (const float2*)coords, tmasks, tmw, tmsum);
    hipLaunchKernelGGL(main_kernel, dim3(BS * QN), dim3(256), 0, stream,
                       logits, pboxes, labels, tboxes, pmasks, (const float2*)coords,
                       tmw, tmsum, out, blockmax, badflag);
    hipLaunchKernelGGL(fix_kernel, dim3(BS * QN), dim3(128), 0, stream,
                       out, blockmax, badflag);
}